// Round 22
// baseline (84.038 us; speedup 1.0000x reference)
//
#include <hip/hip_runtime.h>

typedef __attribute__((ext_vector_type(4))) float f32x4;
typedef __attribute__((ext_vector_type(8))) short bf16x8;

#define S_LEN 4096

__device__ inline short f2bf(float f) {
    union { float f; unsigned u; } v; v.f = f;
    unsigned r = (v.u + 0x7fffu + ((v.u >> 16) & 1u)) >> 16;
    return (short)r;
}
__device__ inline unsigned pack2bf(float a, float b) {
    return (unsigned)(unsigned short)f2bf(a) | ((unsigned)(unsigned short)f2bf(b) << 16);
}
__device__ inline unsigned cvt_pk_bf16(float lo, float hi) {
    unsigned r;
    asm("v_cvt_pk_bf16_f32 %0, %1, %2" : "=v"(r) : "v"(lo), "v"(hi));
    return r;
}
__device__ inline void gload_lds16(const void* g, void* l) {
    __builtin_amdgcn_global_load_lds(
        (const __attribute__((address_space(1))) unsigned int*)g,
        (__attribute__((address_space(3))) unsigned int*)l, 16, 0, 0);
}

// Wsz k-chunk-major, BK=64 steps: Wsz[t*12288 + c8*1536 + g*8 + e] = bf16(W_m[k][c]),
// k = t*64 + c8*8 + e, g = m*64 + c (t 0..15, c8 0..7, e 0..7). [green r18]
__global__ __launch_bounds__(256) void wconv_kernel(const float* __restrict__ Wq,
        const float* __restrict__ Wk, const float* __restrict__ Wv,
        short* __restrict__ Wsz) {
    int idx = blockIdx.x * 256 + threadIdx.x;          // 0..196607
    int t = idx / 12288;
    int rem = idx - t * 12288;
    int c8 = rem / 1536;
    int rem2 = rem - c8 * 1536;
    int g = rem2 >> 3, e = rem2 & 7;
    int k = t * 64 + c8 * 8 + e;
    int m = g >> 6, c = g & 63;
    const float* W = (m == 0) ? Wq : (m == 1) ? Wk : Wv;
    Wsz[idx] = f2bf(W[k * 64 + c]);
}

// BM=32 x BN=96 (col-half h = bid&1), BK=64 -> 16 iterations, grid 1024 = 4 blocks/CU.
// LDS (A 8KB + B 12KB) x2 = 40KB. Stage = 5x16B ops/thread, ALL dests lane-linear
// tid*16 (rule #21); B layout math lives in the per-lane GLOBAL source address.
// Green r20 single-barrier protocol: {STAGE(t+1 -> other buf); compute; vmcnt(0); barrier}.
__global__ __launch_bounds__(256, 2) void qkv_kernel(const float* __restrict__ x,
        const short* __restrict__ Wsz, short* __restrict__ Qb,
        short* __restrict__ Ksz, short* __restrict__ Vsz) {
    __shared__ __align__(16) char lds[2][20480];       // 40 KB: A 8K | B 12K
    const int tid = threadIdx.x;
    const int wv = tid >> 6, lane = tid & 63;
    const int wr = wv & 1, wc = wv >> 1;               // wc 0..1
    const int lr = lane & 15, lg = lane >> 4;
    const int bid = blockIdx.x;
    const int h = bid & 1;                             // col-half: cols h*96..h*96+95
    const int rowbase = (bid >> 1) * 32;

    f32x4 acc[3];
#pragma unroll
    for (int i = 0; i < 3; i++) acc[i] = {0.f, 0.f, 0.f, 0.f};

    // A staging (verbatim green r20): p0 = tid*16 (rows 0..15), p1 = p0+4096 (rows 16..31).
    const int p0 = tid * 16, p1 = tid * 16 + 4096;
    const int r0 = p0 >> 8, c0s = (p0 >> 4) & 15;
    const int r1 = p1 >> 8, c1s = (p1 >> 4) & 15;
    const int g0 = (c0s & 8) | ((c0s & 7) ^ (r0 & 7));
    const int g1 = (c1s & 8) | ((c1s & 7) ^ (r1 & 7));
    const float* asrc0 = x + (size_t)(rowbase + r0) * 1024 + g0 * 4;
    const float* asrc1 = x + (size_t)(rowbase + r1) * 1024 + g1 * 4;

    // B staging, lane-linear dest: LDS byte p = tid*16 + j*4096 (j=0..2) maps to
    // source c8 = p/1536, win = p - c8*1536 -> Wsz + c8*3072 + h*1536 + win.
    const char* wbase = (const char*)Wsz + h * 1536;
    const char* bsrcj[3];
#pragma unroll
    for (int jj = 0; jj < 3; jj++) {
        int p = tid * 16 + jj * 4096;
        int c8 = p / 1536;
        int win = p - c8 * 1536;
        bsrcj[jj] = wbase + c8 * 3072 + win;
    }

#define STAGE(t_, s_)                                                        \
    {                                                                        \
        char* base_ = lds[(s_)];                                             \
        gload_lds16(asrc0 + (t_) * 64, base_ + p0);                          \
        gload_lds16(asrc1 + (t_) * 64, base_ + p1);                          \
        gload_lds16(bsrcj[0] + (t_) * 24576, base_ + 8192 + tid * 16);       \
        gload_lds16(bsrcj[1] + (t_) * 24576, base_ + 12288 + tid * 16);      \
        gload_lds16(bsrcj[2] + (t_) * 24576, base_ + 16384 + tid * 16);      \
    }

    STAGE(0, 0);
    asm volatile("s_waitcnt vmcnt(0)" ::: "memory");
    __builtin_amdgcn_s_barrier();

    const int rowA = wr * 16 + lr;
    const int aswz = rowA & 7;

#pragma unroll
    for (int t = 0; t < 16; t++) {
        if (t + 1 < 16) STAGE(t + 1, (t + 1) & 1);

        const char* Ab = lds[t & 1];
        const char* Bb = lds[t & 1] + 8192;

#pragma unroll
        for (int kh = 0; kh < 2; kh++) {
            int cA0 = kh * 8 + ((lg * 2) ^ aswz);
            int cA1 = kh * 8 + ((lg * 2 + 1) ^ aswz);
            f32x4 a0 = *(const f32x4*)(Ab + rowA * 256 + cA0 * 16);
            f32x4 a1 = *(const f32x4*)(Ab + rowA * 256 + cA1 * 16);
            union { unsigned u[4]; bf16x8 v; } au;
            au.u[0] = cvt_pk_bf16(a0[0], a0[1]);
            au.u[1] = cvt_pk_bf16(a0[2], a0[3]);
            au.u[2] = cvt_pk_bf16(a1[0], a1[1]);
            au.u[3] = cvt_pk_bf16(a1[2], a1[3]);

#pragma unroll
            for (int cf = 0; cf < 3; cf++) {
                int brow = wc * 48 + cf * 16 + lr;       // local col 0..95
                bf16x8 b = *(const bf16x8*)(Bb + (kh * 4 + lg) * 1536 + brow * 16);
                acc[cf] = __builtin_amdgcn_mfma_f32_16x16x32_bf16(au.v, b, acc[cf], 0, 0, 0);
            }
        }

        asm volatile("s_waitcnt vmcnt(0)" ::: "memory");
        __builtin_amdgcn_sched_barrier(0);
        __builtin_amdgcn_s_barrier();
    }
#undef STAGE

#pragma unroll
    for (int cf = 0; cf < 3; cf++) {
        int gcol = h * 96 + wc * 48 + cf * 16 + lr;
        int m = gcol >> 6, cm = gcol & 63;
#pragma unroll
        for (int r = 0; r < 4; r++) {
            int row = rowbase + wr * 16 + lg * 4 + r;
            short bv = f2bf(acc[cf][r]);
            if (m == 0) {
                Qb[(size_t)row * 64 + cm] = bv;
            } else if (m == 1) {
                int b = row >> 12, s12 = row & 4095;
                int tk = s12 >> 6, rr = s12 & 63;
                Ksz[(((size_t)(b * 64 + tk) * 64 + rr) << 6)
                    + (((cm >> 3) ^ (rr & 7)) << 3) + (cm & 7)] = bv;
            } else {
                int b = row >> 12, s12 = row & 4095;
                int tk = s12 >> 6, kk = s12 & 63;
                Vsz[(((size_t)(b * 64 + tk) * 64 + cm) << 6)
                    + (((kk >> 3) ^ (cm & 7)) << 3) + (kk & 7)] = bv;
            }
        }
    }
}

// 4-wave fused attention partial. [green r12/r16, unchanged]
__global__ __launch_bounds__(256, 3) void attn_fused_kernel(const short* __restrict__ Qb,
        const short* __restrict__ Ksz, const short* __restrict__ Vsz,
        float* __restrict__ o_part, float* __restrict__ m_part, float* __restrict__ l_part) {
    __shared__ __align__(16) char kvb2[2][16384];      // K 8K | V 8K per buffer
    __shared__ __align__(16) char Pl[4 * 4096];
    const int tid = threadIdx.x;
    const int wv = tid >> 6, lane = tid & 63;
    const int lr = lane & 15, lg = lane >> 4;

    const int j = blockIdx.x;                  // 0..1087
    const int bb = j / 272;
    int jb = j - bb * 272;
    int qt = 0;
    while (jb >= ((qt + 2) >> 1)) { jb -= (qt + 2) >> 1; qt++; }
    const int c = jb;
    const int t0 = c * 4;                      // first 64-key block
    const int nb = min(4, 2 * qt + 2 - 4 * c); // 64-key blocks in this chunk
    const int qb_w = qt * 128 + wv * 32;       // this wave's q-tile base

    bf16x8 qa[2][2];
#pragma unroll
    for (int qf = 0; qf < 2; qf++)
#pragma unroll
        for (int dk = 0; dk < 2; dk++)
            qa[qf][dk] = *(const bf16x8*)(Qb + (size_t)(bb * S_LEN + qb_w + qf * 16 + lr) * 64 + dk * 32 + lg * 8);

    f32x4 o[2][4];
    float mrun[2] = {-1e30f, -1e30f}, lrun[2] = {0.f, 0.f};
#pragma unroll
    for (int qf = 0; qf < 2; qf++)
#pragma unroll
        for (int df = 0; df < 4; df++) o[qf][df] = {0.f, 0.f, 0.f, 0.f};

    const char* Kg = (const char*)Ksz;
    const char* Vg = (const char*)Vsz;
    char* Pb = Pl + wv * 4096;

#define STAGEKV(t_, s_)                                                       \
    {                                                                         \
        size_t off_ = (size_t)(bb * 64 + t0 + (t_)) * 8192 + tid * 16;        \
        char* d_ = kvb2[(s_)] + tid * 16;                                     \
        gload_lds16(Kg + off_,        d_);                                    \
        gload_lds16(Kg + off_ + 4096, d_ + 4096);                             \
        gload_lds16(Vg + off_,        d_ + 8192);                             \
        gload_lds16(Vg + off_ + 4096, d_ + 12288);                            \
    }

    STAGEKV(0, 0);
    asm volatile("s_waitcnt vmcnt(0)" ::: "memory");
    __builtin_amdgcn_s_barrier();

    for (int t = 0; t < nb; t++) {
        if (t + 1 < nb) STAGEKV(t + 1, (t + 1) & 1);

        const int kv0 = (t0 + t) * 64;
        if (kv0 <= qb_w + 31) {                // wave-uniform skip of masked blocks
            const char* Kl = kvb2[t & 1];
            const char* Vl = Kl + 8192;

            bf16x8 kb[4][2], vb[2][4];
#pragma unroll
            for (int kf = 0; kf < 4; kf++)
#pragma unroll
                for (int dk = 0; dk < 2; dk++) {
                    int r = kf * 16 + lr;
                    kb[kf][dk] = *(const bf16x8*)(Kl + r * 128 + ((((dk << 2) | lg) ^ (r & 7)) << 4));
                }
#pragma unroll
            for (int kk = 0; kk < 2; kk++)
#pragma unroll
                for (int df = 0; df < 4; df++) {
                    int d = df * 16 + lr;
                    vb[kk][df] = *(const bf16x8*)(Vl + d * 128 + ((((kk << 2) | lg) ^ (d & 7)) << 4));
                }

            f32x4 s[2][4];
#pragma unroll
            for (int qf = 0; qf < 2; qf++)
#pragma unroll
                for (int kf = 0; kf < 4; kf++) {
                    f32x4 z = {0.f, 0.f, 0.f, 0.f};
                    z = __builtin_amdgcn_mfma_f32_16x16x32_bf16(kb[kf][0], qa[qf][0], z, 0, 0, 0);
                    s[qf][kf] = __builtin_amdgcn_mfma_f32_16x16x32_bf16(kb[kf][1], qa[qf][1], z, 0, 0, 0);
                }

            const bool needmask = (kv0 + 63) > qb_w;
#pragma unroll
            for (int qf = 0; qf < 2; qf++)
#pragma unroll
                for (int kf = 0; kf < 4; kf++)
#pragma unroll
                    for (int r = 0; r < 4; r++) {
                        float v = s[qf][kf][r] * 0.125f;
                        if (needmask) {
                            int row = qb_w + qf * 16 + lr;
                            int col = kv0 + kf * 16 + lg * 4 + r;
                            if (col > row) v = -1e30f;
                        }
                        s[qf][kf][r] = v;
                    }

#pragma unroll
            for (int qf = 0; qf < 2; qf++) {
                float pm = -1e30f;
#pragma unroll
                for (int kf = 0; kf < 4; kf++)
#pragma unroll
                    for (int r = 0; r < 4; r++) pm = fmaxf(pm, s[qf][kf][r]);
                pm = fmaxf(pm, __shfl_xor(pm, 16, 64));
                pm = fmaxf(pm, __shfl_xor(pm, 32, 64));
                float mnew = fmaxf(mrun[qf], pm);
                float fac = __expf(mrun[qf] - mnew);
                mrun[qf] = mnew;

                const int q = qf * 16 + lr;
                const int swz = (q & 7) << 4;
                float rs = 0.f;
#pragma unroll
                for (int kf = 0; kf < 4; kf++) {
                    float p0 = __expf(s[qf][kf][0] - mnew);
                    float p1 = __expf(s[qf][kf][1] - mnew);
                    float p2 = __expf(s[qf][kf][2] - mnew);
                    float p3 = __expf(s[qf][kf][3] - mnew);
                    rs += (p0 + p1) + (p2 + p3);
                    uint2 w; w.x = pack2bf(p0, p1); w.y = pack2bf(p2, p3);
                    int byt = (q * 128 + kf * 32 + lg * 8) ^ swz;
                    *(uint2*)(Pb + byt) = w;
                }
                rs += __shfl_xor(rs, 16, 64);
                rs += __shfl_xor(rs, 32, 64);
                lrun[qf] = lrun[qf] * fac + rs;
#pragma unroll
                for (int df = 0; df < 4; df++)
#pragma unroll
                    for (int r = 0; r < 4; r++) o[qf][df][r] *= fac;
            }

            bf16x8 pa[2][2];
#pragma unroll
            for (int qf = 0; qf < 2; qf++)
#pragma unroll
                for (int kk = 0; kk < 2; kk++) {
                    int q = qf * 16 + lr;
                    int byt = (q * 128 + kk * 64 + lg * 16) ^ ((q & 7) << 4);
                    pa[qf][kk] = *(const bf16x8*)(Pb + byt);
                }

#pragma unroll
            for (int qf = 0; qf < 2; qf++)
#pragma unroll
                for (int df = 0; df < 4; df++) {
                    o[qf][df] = __builtin_amdgcn_mfma_f32_16x16x32_bf16(vb[0][df], pa[qf][0], o[qf][df], 0, 0, 0);
                    o[qf][df] = __builtin_amdgcn_mfma_f32_16x16x32_bf16(vb[1][df], pa[qf][1], o[qf][df], 0, 0, 0);
                }
        }

        asm volatile("s_waitcnt vmcnt(0)" ::: "memory");
        __builtin_amdgcn_sched_barrier(0);
        __builtin_amdgcn_s_barrier();
    }
#undef STAGEKV

#pragma unroll
    for (int qf = 0; qf < 2; qf++)
#pragma unroll
        for (int df = 0; df < 4; df++)
            *(f32x4*)(o_part + ((size_t)j * 128 + wv * 32 + qf * 16 + lr) * 64 + df * 16 + lg * 4) = o[qf][df];
    if (lg == 0) {
#pragma unroll
        for (int qf = 0; qf < 2; qf++) {
            m_part[(size_t)j * 128 + wv * 32 + qf * 16 + lr] = mrun[qf];
            l_part[(size_t)j * 128 + wv * 32 + qf * 16 + lr] = lrun[qf];
        }
    }
}

// One thread per output element; <=16 chunk partials per row. [green r16]
__global__ __launch_bounds__(256) void combine_kernel(const float* __restrict__ o_part,
        const float* __restrict__ m_part, const float* __restrict__ l_part,
        float* __restrict__ out) {
    const int idx = blockIdx.x * 256 + threadIdx.x;
    const int col = idx & 63;
    const int rowg = idx >> 6;
    const int bb = rowg >> 12;
    const int srow = rowg & 4095;
    const int qt = srow >> 7;
    const int rloc = srow & 127;
    const int h = qt >> 1;
    const int n = (qt + 2) >> 1;
    const int jb0 = bb * 272 + h * (h + 1) + (qt & 1) * (h + 1);

    float M = -1e30f;
    for (int cc = 0; cc < n; cc++) M = fmaxf(M, m_part[(size_t)(jb0 + cc) * 128 + rloc]);
    float L = 0.f, acc = 0.f;
    for (int cc = 0; cc < n; cc++) {
        float w = __expf(m_part[(size_t)(jb0 + cc) * 128 + rloc] - M);
        L += l_part[(size_t)(jb0 + cc) * 128 + rloc] * w;
        acc += o_part[((size_t)(jb0 + cc) * 128 + rloc) * 64 + col] * w;
    }
    out[idx] = acc / L;
}

extern "C" void kernel_launch(void* const* d_in, const int* in_sizes, int n_in,
                              void* d_out, int out_size, void* d_ws, size_t ws_size,
                              hipStream_t stream) {
    const float* x  = (const float*)d_in[0];
    const float* Wq = (const float*)d_in[1];
    const float* Wk = (const float*)d_in[2];
    const float* Wv = (const float*)d_in[3];
    float* out = (float*)d_out;

    char* ws = (char*)d_ws;
    short* Wsz = (short*)(ws);                  // 384 KB (k-chunk-major, BK=64)
    short* Qb  = (short*)(ws + 0x60000);        // 2 MB
    short* Ksz = (short*)(ws + 0x260000);       // 2 MB (swizzled per-64-block)
    short* Vsz = (short*)(ws + 0x460000);       // 2 MB (V^T swizzled per-64-block)

    const int njobs = 1088;                     // 4 batches x 272
    float* o_part = (float*)(ws + 0x660000);    // 1088*128*64*4 = 35.7 MB
    float* m_part = o_part + (size_t)njobs * 128 * 64;
    float* l_part = m_part + (size_t)njobs * 128;

    hipLaunchKernelGGL(wconv_kernel, dim3(768), dim3(256), 0, stream, Wq, Wk, Wv, Wsz);
    hipLaunchKernelGGL(qkv_kernel,  dim3(1024), dim3(256), 0, stream, x, Wsz, Qb, Ksz, Vsz);
    hipLaunchKernelGGL(attn_fused_kernel, dim3(njobs), dim3(256), 0, stream,
                       Qb, Ksz, Vsz, o_part, m_part, l_part);
    hipLaunchKernelGGL(combine_kernel, dim3(4096), dim3(256), 0, stream,
                       o_part, m_part, l_part, out);
}

// Round 23
// 70.777 us; speedup vs baseline: 1.1874x; 1.1874x over previous
//
#include <hip/hip_runtime.h>

typedef __attribute__((ext_vector_type(4))) float f32x4;
typedef __attribute__((ext_vector_type(8))) short bf16x8;

#define S_LEN 4096

__device__ inline short f2bf(float f) {
    union { float f; unsigned u; } v; v.f = f;
    unsigned r = (v.u + 0x7fffu + ((v.u >> 16) & 1u)) >> 16;
    return (short)r;
}
__device__ inline unsigned pack2bf(float a, float b) {
    return (unsigned)(unsigned short)f2bf(a) | ((unsigned)(unsigned short)f2bf(b) << 16);
}
__device__ inline unsigned cvt_pk_bf16(float lo, float hi) {
    unsigned r;
    asm("v_cvt_pk_bf16_f32 %0, %1, %2" : "=v"(r) : "v"(lo), "v"(hi));
    return r;
}
__device__ inline void gload_lds16(const void* g, void* l) {
    __builtin_amdgcn_global_load_lds(
        (const __attribute__((address_space(1))) unsigned int*)g,
        (__attribute__((address_space(3))) unsigned int*)l, 16, 0, 0);
}

// Wsz k-chunk-major, BK=32 (green r16): Wsz[t*6144 + c4*1536 + g*8 + e] = bf16(W_m[k][c]),
// k = t*32 + c4*8 + e, g = m*64 + c (t 0..31, c4 0..3, e 0..7).
__global__ __launch_bounds__(256) void wconv_kernel(const float* __restrict__ Wq,
        const float* __restrict__ Wk, const float* __restrict__ Wv,
        short* __restrict__ Wsz) {
    int idx = blockIdx.x * 256 + threadIdx.x;          // 0..196607
    int t = idx / 6144;
    int rem = idx - t * 6144;
    int c4 = rem / 1536;
    int rem2 = rem - c4 * 1536;
    int g = rem2 >> 3, e = rem2 & 7;
    int k = t * 32 + c4 * 8 + e;
    int m = g >> 6, c = g & 63;
    const float* W = (m == 0) ? Wq : (m == 1) ? Wk : Wv;
    Wsz[idx] = f2bf(W[k * 64 + c]);
}

// BM=64 x BN=192, BK=32, grid 256. 4 waves: wave wv owns rows wv*16..+15, ALL 192 cols
// (acc[12], green r2 structure). Stage = A 8KB (2 ops, chunk^(row&7)) + B 12KB
// (3 ops, linear k-chunk-major) = 5x16B lane-linear ops/thread. Triple buffer 60KB,
// depth-2 prefetch, counted vmcnt(5) (green r16 protocol). Staged total 160MB (vs 256).
__global__ __launch_bounds__(256, 2) void qkv_kernel(const float* __restrict__ x,
        const short* __restrict__ Wsz, short* __restrict__ Qb,
        short* __restrict__ Ksz, short* __restrict__ Vsz) {
    __shared__ __align__(16) char lds[3][20480];       // 60 KB: A 8K | B 12K
    const int tid = threadIdx.x;
    const int wv = tid >> 6, lane = tid & 63;
    const int lr = lane & 15, lg = lane >> 4;
    const int rowbase = blockIdx.x * 64;

    f32x4 acc[12];
#pragma unroll
    for (int i = 0; i < 12; i++) acc[i] = {0.f, 0.f, 0.f, 0.f};

    // A staging: byte p -> row p>>7 (128B/row), chunk (p>>4)&7; src chunk = cL^(row&7).
    const int p0 = tid * 16, p1 = tid * 16 + 4096;
    const int r0 = p0 >> 7, c0L = (p0 >> 4) & 7;
    const int r1 = p1 >> 7, c1L = (p1 >> 4) & 7;
    const float* asrc0 = x + (size_t)(rowbase + r0) * 1024 + ((c0L ^ (r0 & 7)) << 2);
    const float* asrc1 = x + (size_t)(rowbase + r1) * 1024 + ((c1L ^ (r1 & 7)) << 2);
    const char* wsrc = (const char*)Wsz + tid * 16;

#define STAGE(t_, s_)                                                        \
    {                                                                        \
        char* base_ = lds[(s_)];                                             \
        gload_lds16(asrc0 + (t_) * 32, base_ + p0);                          \
        gload_lds16(asrc1 + (t_) * 32, base_ + p1);                          \
        const char* bs_ = wsrc + (t_) * 12288;                               \
        gload_lds16(bs_,        base_ + 8192 + tid * 16);                    \
        gload_lds16(bs_ + 4096, base_ + 12288 + tid * 16);                   \
        gload_lds16(bs_ + 8192, base_ + 16384 + tid * 16);                   \
    }

    STAGE(0, 0);
    STAGE(1, 1);

    const int rowA = wv * 16 + lr;                     // wv*16 % 8 == 0
    const int aswz = rowA & 7;

#pragma unroll
    for (int t = 0; t < 32; t++) {
        if (t < 31) asm volatile("s_waitcnt vmcnt(5)" ::: "memory");
        else        asm volatile("s_waitcnt vmcnt(0)" ::: "memory");
        __builtin_amdgcn_sched_barrier(0);
        __builtin_amdgcn_s_barrier();
        __builtin_amdgcn_sched_barrier(0);
        if (t + 2 < 32) STAGE(t + 2, (t + 2) % 3);

        const char* Ab = lds[t % 3];
        const char* Bb = lds[t % 3] + 8192;

        // A frag: row = rowA, k = lg*8 + j
        f32x4 a0 = *(const f32x4*)(Ab + rowA * 128 + (((lg * 2) ^ aswz) << 4));
        f32x4 a1 = *(const f32x4*)(Ab + rowA * 128 + (((lg * 2 + 1) ^ aswz) << 4));
        union { unsigned u[4]; bf16x8 v; } au;
        au.u[0] = cvt_pk_bf16(a0[0], a0[1]);
        au.u[1] = cvt_pk_bf16(a0[2], a0[3]);
        au.u[2] = cvt_pk_bf16(a1[0], a1[1]);
        au.u[3] = cvt_pk_bf16(a1[2], a1[3]);

#pragma unroll
        for (int cf = 0; cf < 12; cf++) {
            int brow = cf * 16 + lr;
            bf16x8 b = *(const bf16x8*)(Bb + lg * 3072 + brow * 16);
            acc[cf] = __builtin_amdgcn_mfma_f32_16x16x32_bf16(au.v, b, acc[cf], 0, 0, 0);
        }
    }
#undef STAGE

#pragma unroll
    for (int cf = 0; cf < 12; cf++) {
        int gcol = cf * 16 + lr;
        int m = gcol >> 6, cm = gcol & 63;
#pragma unroll
        for (int r = 0; r < 4; r++) {
            int row = rowbase + wv * 16 + lg * 4 + r;
            short bv = f2bf(acc[cf][r]);
            if (m == 0) {
                Qb[(size_t)row * 64 + cm] = bv;
            } else if (m == 1) {
                int b = row >> 12, s12 = row & 4095;
                int tk = s12 >> 6, rr = s12 & 63;
                Ksz[(((size_t)(b * 64 + tk) * 64 + rr) << 6)
                    + (((cm >> 3) ^ (rr & 7)) << 3) + (cm & 7)] = bv;
            } else {
                int b = row >> 12, s12 = row & 4095;
                int tk = s12 >> 6, kk = s12 & 63;
                Vsz[(((size_t)(b * 64 + tk) * 64 + cm) << 6)
                    + (((kk >> 3) ^ (cm & 7)) << 3) + (kk & 7)] = bv;
            }
        }
    }
}

// 4-wave fused attention partial. [green r12/r16/r20, unchanged]
__global__ __launch_bounds__(256, 3) void attn_fused_kernel(const short* __restrict__ Qb,
        const short* __restrict__ Ksz, const short* __restrict__ Vsz,
        float* __restrict__ o_part, float* __restrict__ m_part, float* __restrict__ l_part) {
    __shared__ __align__(16) char kvb2[2][16384];      // K 8K | V 8K per buffer
    __shared__ __align__(16) char Pl[4 * 4096];
    const int tid = threadIdx.x;
    const int wv = tid >> 6, lane = tid & 63;
    const int lr = lane & 15, lg = lane >> 4;

    const int j = blockIdx.x;                  // 0..1087
    const int bb = j / 272;
    int jb = j - bb * 272;
    int qt = 0;
    while (jb >= ((qt + 2) >> 1)) { jb -= (qt + 2) >> 1; qt++; }
    const int c = jb;
    const int t0 = c * 4;                      // first 64-key block
    const int nb = min(4, 2 * qt + 2 - 4 * c); // 64-key blocks in this chunk
    const int qb_w = qt * 128 + wv * 32;       // this wave's q-tile base

    bf16x8 qa[2][2];
#pragma unroll
    for (int qf = 0; qf < 2; qf++)
#pragma unroll
        for (int dk = 0; dk < 2; dk++)
            qa[qf][dk] = *(const bf16x8*)(Qb + (size_t)(bb * S_LEN + qb_w + qf * 16 + lr) * 64 + dk * 32 + lg * 8);

    f32x4 o[2][4];
    float mrun[2] = {-1e30f, -1e30f}, lrun[2] = {0.f, 0.f};
#pragma unroll
    for (int qf = 0; qf < 2; qf++)
#pragma unroll
        for (int df = 0; df < 4; df++) o[qf][df] = {0.f, 0.f, 0.f, 0.f};

    const char* Kg = (const char*)Ksz;
    const char* Vg = (const char*)Vsz;
    char* Pb = Pl + wv * 4096;

#define STAGEKV(t_, s_)                                                       \
    {                                                                         \
        size_t off_ = (size_t)(bb * 64 + t0 + (t_)) * 8192 + tid * 16;        \
        char* d_ = kvb2[(s_)] + tid * 16;                                     \
        gload_lds16(Kg + off_,        d_);                                    \
        gload_lds16(Kg + off_ + 4096, d_ + 4096);                             \
        gload_lds16(Vg + off_,        d_ + 8192);                             \
        gload_lds16(Vg + off_ + 4096, d_ + 12288);                            \
    }

    STAGEKV(0, 0);
    asm volatile("s_waitcnt vmcnt(0)" ::: "memory");
    __builtin_amdgcn_s_barrier();

    for (int t = 0; t < nb; t++) {
        if (t + 1 < nb) STAGEKV(t + 1, (t + 1) & 1);

        const int kv0 = (t0 + t) * 64;
        if (kv0 <= qb_w + 31) {                // wave-uniform skip of masked blocks
            const char* Kl = kvb2[t & 1];
            const char* Vl = Kl + 8192;

            bf16x8 kb[4][2], vb[2][4];
#pragma unroll
            for (int kf = 0; kf < 4; kf++)
#pragma unroll
                for (int dk = 0; dk < 2; dk++) {
                    int r = kf * 16 + lr;
                    kb[kf][dk] = *(const bf16x8*)(Kl + r * 128 + ((((dk << 2) | lg) ^ (r & 7)) << 4));
                }
#pragma unroll
            for (int kk = 0; kk < 2; kk++)
#pragma unroll
                for (int df = 0; df < 4; df++) {
                    int d = df * 16 + lr;
                    vb[kk][df] = *(const bf16x8*)(Vl + d * 128 + ((((kk << 2) | lg) ^ (d & 7)) << 4));
                }

            f32x4 s[2][4];
#pragma unroll
            for (int qf = 0; qf < 2; qf++)
#pragma unroll
                for (int kf = 0; kf < 4; kf++) {
                    f32x4 z = {0.f, 0.f, 0.f, 0.f};
                    z = __builtin_amdgcn_mfma_f32_16x16x32_bf16(kb[kf][0], qa[qf][0], z, 0, 0, 0);
                    s[qf][kf] = __builtin_amdgcn_mfma_f32_16x16x32_bf16(kb[kf][1], qa[qf][1], z, 0, 0, 0);
                }

            const bool needmask = (kv0 + 63) > qb_w;
#pragma unroll
            for (int qf = 0; qf < 2; qf++)
#pragma unroll
                for (int kf = 0; kf < 4; kf++)
#pragma unroll
                    for (int r = 0; r < 4; r++) {
                        float v = s[qf][kf][r] * 0.125f;
                        if (needmask) {
                            int row = qb_w + qf * 16 + lr;
                            int col = kv0 + kf * 16 + lg * 4 + r;
                            if (col > row) v = -1e30f;
                        }
                        s[qf][kf][r] = v;
                    }

#pragma unroll
            for (int qf = 0; qf < 2; qf++) {
                float pm = -1e30f;
#pragma unroll
                for (int kf = 0; kf < 4; kf++)
#pragma unroll
                    for (int r = 0; r < 4; r++) pm = fmaxf(pm, s[qf][kf][r]);
                pm = fmaxf(pm, __shfl_xor(pm, 16, 64));
                pm = fmaxf(pm, __shfl_xor(pm, 32, 64));
                float mnew = fmaxf(mrun[qf], pm);
                float fac = __expf(mrun[qf] - mnew);
                mrun[qf] = mnew;

                const int q = qf * 16 + lr;
                const int swz = (q & 7) << 4;
                float rs = 0.f;
#pragma unroll
                for (int kf = 0; kf < 4; kf++) {
                    float p0 = __expf(s[qf][kf][0] - mnew);
                    float p1 = __expf(s[qf][kf][1] - mnew);
                    float p2 = __expf(s[qf][kf][2] - mnew);
                    float p3 = __expf(s[qf][kf][3] - mnew);
                    rs += (p0 + p1) + (p2 + p3);
                    uint2 w; w.x = pack2bf(p0, p1); w.y = pack2bf(p2, p3);
                    int byt = (q * 128 + kf * 32 + lg * 8) ^ swz;
                    *(uint2*)(Pb + byt) = w;
                }
                rs += __shfl_xor(rs, 16, 64);
                rs += __shfl_xor(rs, 32, 64);
                lrun[qf] = lrun[qf] * fac + rs;
#pragma unroll
                for (int df = 0; df < 4; df++)
#pragma unroll
                    for (int r = 0; r < 4; r++) o[qf][df][r] *= fac;
            }

            bf16x8 pa[2][2];
#pragma unroll
            for (int qf = 0; qf < 2; qf++)
#pragma unroll
                for (int kk = 0; kk < 2; kk++) {
                    int q = qf * 16 + lr;
                    int byt = (q * 128 + kk * 64 + lg * 16) ^ ((q & 7) << 4);
                    pa[qf][kk] = *(const bf16x8*)(Pb + byt);
                }

#pragma unroll
            for (int qf = 0; qf < 2; qf++)
#pragma unroll
                for (int df = 0; df < 4; df++) {
                    o[qf][df] = __builtin_amdgcn_mfma_f32_16x16x32_bf16(vb[0][df], pa[qf][0], o[qf][df], 0, 0, 0);
                    o[qf][df] = __builtin_amdgcn_mfma_f32_16x16x32_bf16(vb[1][df], pa[qf][1], o[qf][df], 0, 0, 0);
                }
        }

        asm volatile("s_waitcnt vmcnt(0)" ::: "memory");
        __builtin_amdgcn_sched_barrier(0);
        __builtin_amdgcn_s_barrier();
    }
#undef STAGEKV

#pragma unroll
    for (int qf = 0; qf < 2; qf++)
#pragma unroll
        for (int df = 0; df < 4; df++)
            *(f32x4*)(o_part + ((size_t)j * 128 + wv * 32 + qf * 16 + lr) * 64 + df * 16 + lg * 4) = o[qf][df];
    if (lg == 0) {
#pragma unroll
        for (int qf = 0; qf < 2; qf++) {
            m_part[(size_t)j * 128 + wv * 32 + qf * 16 + lr] = mrun[qf];
            l_part[(size_t)j * 128 + wv * 32 + qf * 16 + lr] = lrun[qf];
        }
    }
}

// One thread per output element; <=16 chunk partials per row. [green r16]
__global__ __launch_bounds__(256) void combine_kernel(const float* __restrict__ o_part,
        const float* __restrict__ m_part, const float* __restrict__ l_part,
        float* __restrict__ out) {
    const int idx = blockIdx.x * 256 + threadIdx.x;
    const int col = idx & 63;
    const int rowg = idx >> 6;
    const int bb = rowg >> 12;
    const int srow = rowg & 4095;
    const int qt = srow >> 7;
    const int rloc = srow & 127;
    const int h = qt >> 1;
    const int n = (qt + 2) >> 1;
    const int jb0 = bb * 272 + h * (h + 1) + (qt & 1) * (h + 1);

    float M = -1e30f;
    for (int cc = 0; cc < n; cc++) M = fmaxf(M, m_part[(size_t)(jb0 + cc) * 128 + rloc]);
    float L = 0.f, acc = 0.f;
    for (int cc = 0; cc < n; cc++) {
        float w = __expf(m_part[(size_t)(jb0 + cc) * 128 + rloc] - M);
        L += l_part[(size_t)(jb0 + cc) * 128 + rloc] * w;
        acc += o_part[((size_t)(jb0 + cc) * 128 + rloc) * 64 + col] * w;
    }
    out[idx] = acc / L;
}

extern "C" void kernel_launch(void* const* d_in, const int* in_sizes, int n_in,
                              void* d_out, int out_size, void* d_ws, size_t ws_size,
                              hipStream_t stream) {
    const float* x  = (const float*)d_in[0];
    const float* Wq = (const float*)d_in[1];
    const float* Wk = (const float*)d_in[2];
    const float* Wv = (const float*)d_in[3];
    float* out = (float*)d_out;

    char* ws = (char*)d_ws;
    short* Wsz = (short*)(ws);                  // 384 KB (k-chunk-major, BK=32)
    short* Qb  = (short*)(ws + 0x60000);        // 2 MB
    short* Ksz = (short*)(ws + 0x260000);       // 2 MB (swizzled per-64-block)
    short* Vsz = (short*)(ws + 0x460000);       // 2 MB (V^T swizzled per-64-block)

    const int njobs = 1088;                     // 4 batches x 272
    float* o_part = (float*)(ws + 0x660000);    // 1088*128*64*4 = 35.7 MB
    float* m_part = o_part + (size_t)njobs * 128 * 64;
    float* l_part = m_part + (size_t)njobs * 128;

    hipLaunchKernelGGL(wconv_kernel, dim3(768), dim3(256), 0, stream, Wq, Wk, Wv, Wsz);
    hipLaunchKernelGGL(qkv_kernel,  dim3(256), dim3(256), 0, stream, x, Wsz, Qb, Ksz, Vsz);
    hipLaunchKernelGGL(attn_fused_kernel, dim3(njobs), dim3(256), 0, stream,
                       Qb, Ksz, Vsz, o_part, m_part, l_part);
    hipLaunchKernelGGL(combine_kernel, dim3(4096), dim3(256), 0, stream,
                       o_part, m_part, l_part, out);
}